// Round 2
// baseline (38581.989 us; speedup 1.0000x reference)
//
#include <hip/hip_runtime.h>
#include <cmath>

#define BB 128
#define TT 512
#define II 256
#define HH 1024
#define K0 (II + HH)   // 1280 = 40 k-frags, 5 per wave
#define K1 (2 * HH)    // 2048 = 64 k-frags, 8 per wave

typedef _Float16 half4v __attribute__((ext_vector_type(4)));
typedef _Float16 half8  __attribute__((ext_vector_type(8)));
typedef float    f32x4  __attribute__((ext_vector_type(4)));

__device__ __forceinline__ float sigmoidf_(float x) { return 1.0f / (1.0f + __expf(-x)); }

// ---- convert x to fp16 ----
__global__ __launch_bounds__(256) void cvt_x_kernel(const float* __restrict__ x,
                                                    _Float16* __restrict__ x16, int n4) {
  int i = blockIdx.x * blockDim.x + threadIdx.x;
  if (i >= n4) return;
  const float4 v = ((const float4*)x)[i];
  half4v o = { (_Float16)v.x, (_Float16)v.y, (_Float16)v.z, (_Float16)v.w };
  ((half4v*)x16)[i] = o;
}

// ---- build gate-interleaved fp16 weight [4096][Kin+HH]; row' = 4*j + gate ----
__global__ __launch_bounds__(256) void prep_w_kernel(const float* __restrict__ Wih,
    const float* __restrict__ Whh, const float* __restrict__ bih, const float* __restrict__ bhh,
    _Float16* __restrict__ Wr, float* __restrict__ biasr, int Kin) {
  const int Ktot = Kin + HH;
  const int row  = blockIdx.y;
  const int k    = blockIdx.x * blockDim.x + threadIdx.x;
  const int jj = row >> 2, gate = row & 3;
  const int orow = gate * HH + jj;
  if (k < Ktot) {
    float v = (k < Kin) ? Wih[(size_t)orow * Kin + k] : Whh[(size_t)orow * HH + (k - Kin)];
    Wr[(size_t)row * Ktot + k] = (_Float16)v;
  }
  if (blockIdx.x == 0 && threadIdx.x == 0) biasr[row] = bih[orow] + bhh[orow];
}

// ---- persistent LSTM: weights in registers, grid barrier per timestep ----
// 256 WGs x 512 thr. CU owns 16 reordered rows of EACH layer (hidden j = 4*bid..4*bid+3).
// 8 waves K-split; LDS partial reduce; after reduce wave w owns batch cols 16w..16w+15.
__global__ __launch_bounds__(512, 2) void lstm_persist(
    const _Float16* __restrict__ w0r, const _Float16* __restrict__ w1r,
    const float* __restrict__ bias0, const float* __restrict__ bias1,
    const _Float16* __restrict__ x16,
    _Float16* __restrict__ h0buf, _Float16* __restrict__ h1buf,
    unsigned int* cnt)
{
  __shared__ float red[8 * 2048];   // 64KB: 8 wave-sections of 16x128 f32
  const int tid  = threadIdx.x;
  const int lane = tid & 63;
  const int wid  = tid >> 6;
  const int l15  = lane & 15;
  const int kl   = lane >> 4;
  const int bid  = blockIdx.x;

  union H8 { half8 v8; half4v v4[2]; };

  // ---- A tiles -> registers (stay live for all 513 steps) ----
  half8 A0[5], A1[8];
  {
    const _Float16* base0 = w0r + (size_t)(16 * bid + l15) * K0 + kl * 4;
    #pragma unroll
    for (int f = 0; f < 5; ++f) {
      const int k = (5 * wid + f) * 32;
      H8 u; u.v4[0] = *(const half4v*)(base0 + k);
            u.v4[1] = *(const half4v*)(base0 + k + 16);
      A0[f] = u.v8;
    }
    const _Float16* base1 = w1r + (size_t)(16 * bid + l15) * K1 + kl * 4;
    #pragma unroll
    for (int f = 0; f < 8; ++f) {
      const int k = (8 * wid + f) * 32;
      H8 u; u.v4[0] = *(const half4v*)(base1 + k);
            u.v4[1] = *(const half4v*)(base1 + k + 16);
      A1[f] = u.v8;
    }
  }
  const f32x4 bs0 = *(const f32x4*)(bias0 + 16 * bid + kl * 4);
  const f32x4 bs1 = *(const f32x4*)(bias1 + 16 * bid + kl * 4);

  const int jj = 4 * bid + kl;    // hidden unit this lane owns (both layers)
  const int bb = 16 * wid + l15;  // batch element this lane owns
  float c0 = 0.f, c1 = 0.f;       // cell states live in registers
  bool dead = false;

  #pragma unroll 1
  for (int tau = 0; tau <= TT; ++tau) {
    const _Float16* h0prev = h0buf + ((tau + 1) & 1) * (BB * HH); // h0_{tau-1}
    _Float16*       h0w    = h0buf + ((tau    ) & 1) * (BB * HH); // h0_tau
    const _Float16* h1prev = h1buf + ((tau    ) & 1) * (BB * HH); // h1_{tau-2}
    _Float16*       h1w    = h1buf + ((tau + 1) & 1) * (BB * HH); // h1_{tau-1}

    // ---------------- layer 0: gates for rows 16*bid.., step tau ----------------
    if (tau < TT) {
      f32x4 acc[8];
      #pragma unroll
      for (int bf = 0; bf < 8; ++bf) acc[bf] = (f32x4){0.f, 0.f, 0.f, 0.f};

      #pragma unroll
      for (int f = 0; f < 5; ++f) {
        const int g  = 5 * wid + f;          // global k-frag 0..39
        const int kb = 32 * g + 4 * kl;
        const bool isx = (32 * g) < II;      // frag entirely in x (boundary 256 = 8 frags)
        const _Float16* s = isx ? (x16 + (size_t)tau * II + kb) : (h0prev + (kb - II));
        const size_t bstr = isx ? (size_t)(TT * II) : (size_t)HH;
        #pragma unroll
        for (int bf = 0; bf < 8; ++bf) {
          const _Float16* p = s + (size_t)(16 * bf + l15) * bstr;
          H8 u; u.v4[0] = *(const half4v*)(p);
                u.v4[1] = *(const half4v*)(p + 16);
          acc[bf] = __builtin_amdgcn_mfma_f32_16x16x32_f16(A0[f], u.v8, acc[bf], 0, 0, 0);
        }
      }
      __syncthreads();                        // red free from previous step
      #pragma unroll
      for (int bf = 0; bf < 8; ++bf)
        *(f32x4*)&red[wid * 2048 + bf * 256 + lane * 4] = acc[bf];
      __syncthreads();
      f32x4 r = {0.f, 0.f, 0.f, 0.f};
      #pragma unroll
      for (int s = 0; s < 8; ++s)
        r += *(const f32x4*)&red[s * 2048 + wid * 256 + lane * 4];
      r += bs0;
      const float gi = sigmoidf_(r[0]);
      const float gf = sigmoidf_(r[1]);
      const float gg = tanhf(r[2]);
      const float go = sigmoidf_(r[3]);
      c0 = gf * c0 + gi * gg;
      h0w[(size_t)bb * HH + jj] = (_Float16)(go * tanhf(c0));
    }

    // ---------------- layer 1: step tau-1 (feed h0_{tau-1}, rec h1_{tau-2}) ----------------
    if (tau >= 1) {
      f32x4 acc[8];
      #pragma unroll
      for (int bf = 0; bf < 8; ++bf) acc[bf] = (f32x4){0.f, 0.f, 0.f, 0.f};

      #pragma unroll
      for (int f = 0; f < 8; ++f) {
        const int g  = 8 * wid + f;          // global k-frag 0..63
        const int kb = 32 * g + 4 * kl;
        const bool isfeed = (32 * g) < HH;   // first 1024 = h0_t feed, rest = h1 recurrent
        const _Float16* s = isfeed ? (h0prev + kb) : (h1prev + (kb - HH));
        #pragma unroll
        for (int bf = 0; bf < 8; ++bf) {
          const _Float16* p = s + (size_t)(16 * bf + l15) * HH;
          H8 u; u.v4[0] = *(const half4v*)(p);
                u.v4[1] = *(const half4v*)(p + 16);
          acc[bf] = __builtin_amdgcn_mfma_f32_16x16x32_f16(A1[f], u.v8, acc[bf], 0, 0, 0);
        }
      }
      __syncthreads();                        // red free from layer-0 reduce reads
      #pragma unroll
      for (int bf = 0; bf < 8; ++bf)
        *(f32x4*)&red[wid * 2048 + bf * 256 + lane * 4] = acc[bf];
      __syncthreads();
      f32x4 r = {0.f, 0.f, 0.f, 0.f};
      #pragma unroll
      for (int s = 0; s < 8; ++s)
        r += *(const f32x4*)&red[s * 2048 + wid * 256 + lane * 4];
      r += bs1;
      const float gi = sigmoidf_(r[0]);
      const float gf = sigmoidf_(r[1]);
      const float gg = tanhf(r[2]);
      const float go = sigmoidf_(r[3]);
      c1 = gf * c1 + gi * gg;
      h1w[(size_t)bb * HH + jj] = (_Float16)(go * tanhf(c1));
    }

    // ---------------- grid barrier (skip after final step) ----------------
    if (tau < TT) {
      __syncthreads();
      if (tid == 0) {
        __threadfence();
        __hip_atomic_fetch_add(cnt, 1u, __ATOMIC_ACQ_REL, __HIP_MEMORY_SCOPE_AGENT);
        const unsigned int target = 256u * (unsigned int)(tau + 1);
        if (!dead) {
          int guard = 0;
          while (__hip_atomic_load(cnt, __ATOMIC_ACQUIRE, __HIP_MEMORY_SCOPE_AGENT) < target) {
            if (++guard > (1 << 22)) { dead = true; break; }   // escape hatch: wrong-but-no-hang
          }
        }
        __threadfence();
      }
      __syncthreads();
    }
  }
}

// ---- final projection: out[b][o] = h1_last[b] . Wfc[o] + bfc[o] ----
__global__ __launch_bounds__(128) void fc_kernel(const _Float16* __restrict__ h,
    const float* __restrict__ Wfc, const float* __restrict__ bfc, float* __restrict__ out) {
  const int b = blockIdx.x;
  const int o = threadIdx.x;
  const _Float16* hr = h + (size_t)b * HH;
  const float* wr = Wfc + (size_t)o * HH;
  float s = 0.f;
  #pragma unroll 4
  for (int k = 0; k < HH; k += 4) {
    float4 w = *(const float4*)(wr + k);
    half4v hv = *(const half4v*)(hr + k);
    s += (float)hv[0]*w.x + (float)hv[1]*w.y + (float)hv[2]*w.z + (float)hv[3]*w.w;
  }
  out[(size_t)b * 128 + o] = s + bfc[o];
}

extern "C" void kernel_launch(void* const* d_in, const int* in_sizes, int n_in,
                              void* d_out, int out_size, void* d_ws, size_t ws_size,
                              hipStream_t stream) {
  const float* x    = (const float*)d_in[0];
  const float* Wih0 = (const float*)d_in[1];
  const float* Whh0 = (const float*)d_in[2];
  const float* bih0 = (const float*)d_in[3];
  const float* bhh0 = (const float*)d_in[4];
  const float* Wih1 = (const float*)d_in[5];
  const float* Whh1 = (const float*)d_in[6];
  const float* bih1 = (const float*)d_in[7];
  const float* bhh1 = (const float*)d_in[8];
  const float* Wfc  = (const float*)d_in[9];
  const float* bfc  = (const float*)d_in[10];
  float* out = (float*)d_out;

  char* ws = (char*)d_ws;
  size_t off = 0;
  auto alloc = [&](size_t bytes) -> void* {
    void* p = ws + off;
    off += (bytes + 255) & ~(size_t)255;
    return p;
  };
  _Float16* x16 = (_Float16*)alloc((size_t)BB * TT * II * 2);
  _Float16* w0r = (_Float16*)alloc((size_t)4096 * K0 * 2);
  _Float16* w1r = (_Float16*)alloc((size_t)4096 * K1 * 2);
  float* bias0  = (float*)alloc(4096 * 4);
  float* bias1  = (float*)alloc(4096 * 4);
  const size_t stateBytes = 256 + (size_t)2 * BB * HH * 2 * 2;  // cnt + h0 pingpong + h1 pingpong
  char* states  = (char*)alloc(stateBytes);
  unsigned int* cnt = (unsigned int*)states;
  _Float16* h0buf = (_Float16*)(states + 256);
  _Float16* h1buf = h0buf + 2 * BB * HH;

  hipMemsetAsync(states, 0, stateBytes, stream);

  {
    int n4 = BB * TT * II / 4;
    cvt_x_kernel<<<dim3((n4 + 255) / 256), 256, 0, stream>>>(x, x16, n4);
  }
  prep_w_kernel<<<dim3((K0 + 255) / 256, 4096), 256, 0, stream>>>(Wih0, Whh0, bih0, bhh0, w0r, bias0, II);
  prep_w_kernel<<<dim3((K1 + 255) / 256, 4096), 256, 0, stream>>>(Wih1, Whh1, bih1, bhh1, w1r, bias1, HH);

  void* args[] = { (void*)&w0r, (void*)&w1r, (void*)&bias0, (void*)&bias1,
                   (void*)&x16, (void*)&h0buf, (void*)&h1buf, (void*)&cnt };
  hipLaunchCooperativeKernel((void*)lstm_persist, dim3(256), dim3(512), args, 0, stream);

  fc_kernel<<<dim3(BB), 128, 0, stream>>>(h1buf + (size_t)BB * HH, Wfc, bfc, out);
}

// Round 3
// 26233.255 us; speedup vs baseline: 1.4707x; 1.4707x over previous
//
#include <hip/hip_runtime.h>
#include <cmath>

#define BB 128
#define TT 512
#define II 256
#define HH 1024
#define K0 (II + HH)   // 1280 = 40 k-frags, 5 per wave
#define K1 (2 * HH)    // 2048 = 64 k-frags, 8 per wave

typedef _Float16 half4v __attribute__((ext_vector_type(4)));
typedef _Float16 half8  __attribute__((ext_vector_type(8)));
typedef float    f32x4  __attribute__((ext_vector_type(4)));

__device__ __forceinline__ float sigmoidf_(float x) { return 1.0f / (1.0f + __expf(-x)); }

// K-perm within each 32-block: logical o = 16*half + 4*kl + e  ->  storage p = 8*kl + 4*half + e
// so a lane's MFMA fragment (elems {4kl..4kl+3, 16+4kl..+3}) is 8 contiguous halfs at p = 8*kl.
__device__ __host__ __forceinline__ int invP(int p) {       // storage -> logical
  return 16 * ((p >> 2) & 1) + 4 * (p >> 3) + (p & 3);
}
__device__ __forceinline__ int permP(int o) {               // logical -> storage
  return 8 * ((o & 15) >> 2) + 4 * (o >> 4) + (o & 3);
}

// ---- convert x fp32 [B][T][I] -> fp16 [T][B][permI] ----
__global__ __launch_bounds__(256) void cvt_x_kernel(const float* __restrict__ x,
                                                    _Float16* __restrict__ x16) {
  const int n = blockIdx.x * blockDim.x + threadIdx.x;   // one half8 store each
  const int i8    = n & 31;            // store-block of 8 within the I row
  const int rowid = n >> 5;            // t*BB + b
  const int t = rowid >> 7;            // /BB
  const int b = rowid & (BB - 1);
  const int g  = i8 >> 2;
  const int kl = i8 & 3;
  const float* src = x + ((size_t)b * TT + t) * II + 32 * g;
  const float4 lo = *(const float4*)(src + 4 * kl);
  const float4 hi = *(const float4*)(src + 16 + 4 * kl);
  half8 o = { (_Float16)lo.x, (_Float16)lo.y, (_Float16)lo.z, (_Float16)lo.w,
              (_Float16)hi.x, (_Float16)hi.y, (_Float16)hi.z, (_Float16)hi.w };
  *(half8*)(x16 + (size_t)rowid * II + 8 * i8) = o;
}

// ---- gate-interleaved + K-permuted fp16 weight [4096][Kin+HH]; row' = 4*j + gate ----
__global__ __launch_bounds__(256) void prep_w_kernel(const float* __restrict__ Wih,
    const float* __restrict__ Whh, const float* __restrict__ bih, const float* __restrict__ bhh,
    _Float16* __restrict__ Wr, float* __restrict__ biasr, int Kin) {
  const int Ktot = Kin + HH;
  const int row  = blockIdx.y;
  const int k    = blockIdx.x * blockDim.x + threadIdx.x;   // storage index
  const int jj = row >> 2, gate = row & 3;
  const int orow = gate * HH + jj;
  if (k < Ktot) {
    const int klog = 32 * (k >> 5) + invP(k & 31);
    float v = (klog < Kin) ? Wih[(size_t)orow * Kin + klog] : Whh[(size_t)orow * HH + (klog - Kin)];
    Wr[(size_t)row * Ktot + k] = (_Float16)v;
  }
  if (blockIdx.x == 0 && threadIdx.x == 0) biasr[row] = bih[orow] + bhh[orow];
}

// ---- K-permuted copy of Wfc (so fc can read perm'd h sequentially) ----
__global__ __launch_bounds__(256) void prep_wfc_kernel(const float* __restrict__ Wfc,
                                                       float* __restrict__ wfcp) {
  const int n = blockIdx.x * blockDim.x + threadIdx.x;      // o*HH + k_store
  const int k = n & (HH - 1);
  const int o = n >> 10;
  wfcp[n] = Wfc[(size_t)o * HH + 32 * (k >> 5) + invP(k & 31)];
}

#define LOADG(U, S, ST) \
  { _Pragma("unroll") for (int bf_ = 0; bf_ < 8; ++bf_) \
      U[bf_] = *(const half8*)((S) + (size_t)(16 * bf_ + l15) * (ST)); }

#define MFMAG(U, AF) \
  { _Pragma("unroll") for (int bf_ = 0; bf_ < 8; ++bf_) \
      acc[bf_] = __builtin_amdgcn_mfma_f32_16x16x32_f16((AF), U[bf_], acc[bf_], 0, 0, 0); }

// ---- persistent LSTM: weights in registers, triple-buffered B prefetch, grid barrier ----
__global__ __launch_bounds__(512, 2) void lstm_persist(
    const _Float16* __restrict__ w0r, const _Float16* __restrict__ w1r,
    const float* __restrict__ bias0, const float* __restrict__ bias1,
    const _Float16* __restrict__ x16,
    _Float16* __restrict__ h0buf, _Float16* __restrict__ h1buf,
    unsigned int* cnt)
{
  __shared__ float red[8 * 2048];   // 64KB
  const int tid  = threadIdx.x;
  const int lane = tid & 63;
  const int wid  = tid >> 6;
  const int l15  = lane & 15;
  const int kl   = lane >> 4;
  const int bid  = blockIdx.x;

  // ---- A tiles -> registers, one contiguous half8 per frag (perm'd storage) ----
  half8 A0[5], A1[8];
  {
    const _Float16* base0 = w0r + (size_t)(16 * bid + l15) * K0 + 8 * kl;
    #pragma unroll
    for (int f = 0; f < 5; ++f) A0[f] = *(const half8*)(base0 + 32 * (5 * wid + f));
    const _Float16* base1 = w1r + (size_t)(16 * bid + l15) * K1 + 8 * kl;
    #pragma unroll
    for (int f = 0; f < 8; ++f) A1[f] = *(const half8*)(base1 + 32 * (8 * wid + f));
  }
  const f32x4 bs0 = *(const f32x4*)(bias0 + 16 * bid + kl * 4);
  const f32x4 bs1 = *(const f32x4*)(bias1 + 16 * bid + kl * 4);

  const int jj     = 4 * bid + kl;                       // logical hidden unit this lane owns
  const int jstore = 32 * (jj >> 5) + permP(jj & 31);    // perm'd storage index for h writes
  const int bb     = 16 * wid + l15;                     // batch element this lane owns
  float c0 = 0.f, c1 = 0.f;
  bool dead = false;

  #pragma unroll 1
  for (int tau = 0; tau <= TT; ++tau) {
    const _Float16* h0prev = h0buf + ((tau + 1) & 1) * (BB * HH); // h0_{tau-1}
    _Float16*       h0w    = h0buf + ((tau    ) & 1) * (BB * HH); // h0_tau
    const _Float16* h1prev = h1buf + ((tau    ) & 1) * (BB * HH); // h1_{tau-2}
    _Float16*       h1w    = h1buf + ((tau + 1) & 1) * (BB * HH); // h1_{tau-1}

    // ---------------- layer 0 ----------------
    if (tau < TT) {
      const _Float16* xt = x16 + (size_t)tau * (BB * II);
      f32x4 acc[8];
      #pragma unroll
      for (int bf = 0; bf < 8; ++bf) acc[bf] = (f32x4){0.f, 0.f, 0.f, 0.f};

      half8 Ua[8], Ub[8], Uc[8];
      const _Float16* s_; size_t st_;
      auto src0 = [&](int f) {
        const int g = 5 * wid + f;
        if (g < 8) { s_ = xt + 32 * g + 8 * kl; st_ = II; }
        else       { s_ = h0prev + 32 * (g - 8) + 8 * kl; st_ = HH; }
      };
      src0(0); LOADG(Ua, s_, st_);
      src0(1); LOADG(Ub, s_, st_);
      src0(2); LOADG(Uc, s_, st_);
      MFMAG(Ua, A0[0]); src0(3); LOADG(Ua, s_, st_);
      MFMAG(Ub, A0[1]); src0(4); LOADG(Ub, s_, st_);
      MFMAG(Uc, A0[2]);
      MFMAG(Ua, A0[3]);
      MFMAG(Ub, A0[4]);

      __syncthreads();
      #pragma unroll
      for (int bf = 0; bf < 8; ++bf)
        *(f32x4*)&red[wid * 2048 + bf * 256 + lane * 4] = acc[bf];
      __syncthreads();
      f32x4 r = {0.f, 0.f, 0.f, 0.f};
      #pragma unroll
      for (int s = 0; s < 8; ++s)
        r += *(const f32x4*)&red[s * 2048 + wid * 256 + lane * 4];
      r += bs0;
      const float gi = sigmoidf_(r[0]);
      const float gf = sigmoidf_(r[1]);
      const float gg = tanhf(r[2]);
      const float go = sigmoidf_(r[3]);
      c0 = gf * c0 + gi * gg;
      h0w[(size_t)bb * HH + jstore] = (_Float16)(go * tanhf(c0));
    }

    // ---------------- layer 1 (step tau-1) ----------------
    if (tau >= 1) {
      f32x4 acc[8];
      #pragma unroll
      for (int bf = 0; bf < 8; ++bf) acc[bf] = (f32x4){0.f, 0.f, 0.f, 0.f};

      half8 Ua[8], Ub[8], Uc[8];
      // waves 0..3: all 8 frags from h0prev (feed); waves 4..7: all from h1prev (recurrent)
      const _Float16* sb = (wid < 4) ? (h0prev + 256 * wid + 8 * kl)
                                     : (h1prev + 256 * (wid - 4) + 8 * kl);
      LOADG(Ua, sb +   0, HH);
      LOADG(Ub, sb +  32, HH);
      LOADG(Uc, sb +  64, HH);
      MFMAG(Ua, A1[0]); LOADG(Ua, sb +  96, HH);
      MFMAG(Ub, A1[1]); LOADG(Ub, sb + 128, HH);
      MFMAG(Uc, A1[2]); LOADG(Uc, sb + 160, HH);
      MFMAG(Ua, A1[3]); LOADG(Ua, sb + 192, HH);
      MFMAG(Ub, A1[4]); LOADG(Ub, sb + 224, HH);
      MFMAG(Uc, A1[5]);
      MFMAG(Ua, A1[6]);
      MFMAG(Ub, A1[7]);

      __syncthreads();
      #pragma unroll
      for (int bf = 0; bf < 8; ++bf)
        *(f32x4*)&red[wid * 2048 + bf * 256 + lane * 4] = acc[bf];
      __syncthreads();
      f32x4 r = {0.f, 0.f, 0.f, 0.f};
      #pragma unroll
      for (int s = 0; s < 8; ++s)
        r += *(const f32x4*)&red[s * 2048 + wid * 256 + lane * 4];
      r += bs1;
      const float gi = sigmoidf_(r[0]);
      const float gf = sigmoidf_(r[1]);
      const float gg = tanhf(r[2]);
      const float go = sigmoidf_(r[3]);
      c1 = gf * c1 + gi * gg;
      h1w[(size_t)bb * HH + jstore] = (_Float16)(go * tanhf(c1));
    }

    // ---------------- grid barrier ----------------
    if (tau < TT) {
      __syncthreads();
      if (tid == 0) {
        __threadfence();
        __hip_atomic_fetch_add(cnt, 1u, __ATOMIC_ACQ_REL, __HIP_MEMORY_SCOPE_AGENT);
        const unsigned int target = 256u * (unsigned int)(tau + 1);
        if (!dead) {
          int guard = 0;
          while (__hip_atomic_load(cnt, __ATOMIC_ACQUIRE, __HIP_MEMORY_SCOPE_AGENT) < target) {
            __builtin_amdgcn_s_sleep(1);
            if (++guard > (1 << 20)) { dead = true; break; }   // escape hatch
          }
        }
        __threadfence();
      }
      __syncthreads();
    }
  }
}

// ---- final projection on perm'd h + perm'd Wfc ----
__global__ __launch_bounds__(128) void fc_kernel(const _Float16* __restrict__ h,
    const float* __restrict__ wfcp, const float* __restrict__ bfc, float* __restrict__ out) {
  const int b = blockIdx.x;
  const int o = threadIdx.x;
  const _Float16* hr = h + (size_t)b * HH;
  const float* wr = wfcp + (size_t)o * HH;
  float s = 0.f;
  #pragma unroll 4
  for (int k = 0; k < HH; k += 4) {
    float4 w = *(const float4*)(wr + k);
    half4v hv = *(const half4v*)(hr + k);
    s += (float)hv[0]*w.x + (float)hv[1]*w.y + (float)hv[2]*w.z + (float)hv[3]*w.w;
  }
  out[(size_t)b * 128 + o] = s + bfc[o];
}

extern "C" void kernel_launch(void* const* d_in, const int* in_sizes, int n_in,
                              void* d_out, int out_size, void* d_ws, size_t ws_size,
                              hipStream_t stream) {
  const float* x    = (const float*)d_in[0];
  const float* Wih0 = (const float*)d_in[1];
  const float* Whh0 = (const float*)d_in[2];
  const float* bih0 = (const float*)d_in[3];
  const float* bhh0 = (const float*)d_in[4];
  const float* Wih1 = (const float*)d_in[5];
  const float* Whh1 = (const float*)d_in[6];
  const float* bih1 = (const float*)d_in[7];
  const float* bhh1 = (const float*)d_in[8];
  const float* Wfc  = (const float*)d_in[9];
  const float* bfc  = (const float*)d_in[10];
  float* out = (float*)d_out;

  char* ws = (char*)d_ws;
  size_t off = 0;
  auto alloc = [&](size_t bytes) -> void* {
    void* p = ws + off;
    off += (bytes + 255) & ~(size_t)255;
    return p;
  };
  _Float16* x16 = (_Float16*)alloc((size_t)BB * TT * II * 2);
  _Float16* w0r = (_Float16*)alloc((size_t)4096 * K0 * 2);
  _Float16* w1r = (_Float16*)alloc((size_t)4096 * K1 * 2);
  float* bias0  = (float*)alloc(4096 * 4);
  float* bias1  = (float*)alloc(4096 * 4);
  float* wfcp   = (float*)alloc((size_t)128 * HH * 4);
  const size_t stateBytes = 256 + (size_t)2 * BB * HH * 2 * 2;
  char* states  = (char*)alloc(stateBytes);
  unsigned int* cnt = (unsigned int*)states;
  _Float16* h0buf = (_Float16*)(states + 256);
  _Float16* h1buf = h0buf + 2 * BB * HH;

  hipMemsetAsync(states, 0, stateBytes, stream);

  cvt_x_kernel<<<dim3(BB * TT * II / 8 / 256), 256, 0, stream>>>(x, x16);
  prep_w_kernel<<<dim3(K0 / 256, 4096), 256, 0, stream>>>(Wih0, Whh0, bih0, bhh0, w0r, bias0, II);
  prep_w_kernel<<<dim3(K1 / 256, 4096), 256, 0, stream>>>(Wih1, Whh1, bih1, bhh1, w1r, bias1, HH);
  prep_wfc_kernel<<<dim3(128 * HH / 256), 256, 0, stream>>>(Wfc, wfcp);

  void* args[] = { (void*)&w0r, (void*)&w1r, (void*)&bias0, (void*)&bias1,
                   (void*)&x16, (void*)&h0buf, (void*)&h1buf, (void*)&cnt };
  hipLaunchCooperativeKernel((void*)lstm_persist, dim3(256), dim3(512), args, 0, stream);

  fc_kernel<<<dim3(BB), 128, 0, stream>>>(h1buf + (size_t)BB * HH, wfcp, bfc, out);
}

// Round 4
// 18785.349 us; speedup vs baseline: 2.0538x; 1.3965x over previous
//
#include <hip/hip_runtime.h>
#include <cmath>

#define BB 128
#define TT 512
#define II 256
#define HH 1024
#define K0 (II + HH)   // 1280 = 40 k-frags, 5 per wave
#define K1 (2 * HH)    // 2048 = 64 k-frags, 8 per wave

typedef _Float16 half4v __attribute__((ext_vector_type(4)));
typedef _Float16 half8  __attribute__((ext_vector_type(8)));
typedef float    f32x4  __attribute__((ext_vector_type(4)));

__device__ __forceinline__ float sigmoidf_(float x) { return 1.0f / (1.0f + __expf(-x)); }

// K-perm within each 32-block: storage p -> logical o = 16*((p>>2)&1) + 4*(p>>3) + (p&3)
// so a lane's MFMA fragment (elems {4kl..+3, 16+4kl..+3}) = 8 contiguous halfs at p = 8*kl.
__device__ __host__ __forceinline__ int invP(int p) {
  return 16 * ((p >> 2) & 1) + 4 * (p >> 3) + (p & 3);
}
__device__ __forceinline__ int permP(int o) {
  return 8 * ((o & 15) >> 2) + 4 * (o >> 4) + (o & 3);
}

// ---- convert x fp32 [B][T][I] -> fp16 frag-major [T][g=I/32][B][32perm] ----
__global__ __launch_bounds__(256) void cvt_x_kernel(const float* __restrict__ x,
                                                    _Float16* __restrict__ x16) {
  const int n = blockIdx.x * blockDim.x + threadIdx.x;   // one half8 store each
  const int q   = n & 3;               // which 8-chunk within 32-block (= kl)
  const int b   = (n >> 2) & (BB - 1);
  const int tg  = n >> 9;              // t*8 + g
  const int t = tg >> 3;
  const int g = tg & 7;
  const float* src = x + ((size_t)b * TT + t) * II + 32 * g;
  // storage p = 8*q + e (e=0..7): logical = invP(p)
  const float4 lo = *(const float4*)(src + 4 * q);        // logical 4q..4q+3  -> p 8q..8q+3
  const float4 hi = *(const float4*)(src + 16 + 4 * q);   // logical 16+4q..+3 -> p 8q+4..+7
  half8 o = { (_Float16)lo.x, (_Float16)lo.y, (_Float16)lo.z, (_Float16)lo.w,
              (_Float16)hi.x, (_Float16)hi.y, (_Float16)hi.z, (_Float16)hi.w };
  *(half8*)(x16 + ((size_t)tg * BB + b) * 32 + 8 * q) = o;
}

// ---- gate-interleaved + K-permuted fp16 weight [4096][Kin+HH]; row' = 4*j + gate ----
__global__ __launch_bounds__(256) void prep_w_kernel(const float* __restrict__ Wih,
    const float* __restrict__ Whh, const float* __restrict__ bih, const float* __restrict__ bhh,
    _Float16* __restrict__ Wr, float* __restrict__ biasr, int Kin) {
  const int Ktot = Kin + HH;
  const int row  = blockIdx.y;
  const int k    = blockIdx.x * blockDim.x + threadIdx.x;   // storage index
  const int jj = row >> 2, gate = row & 3;
  const int orow = gate * HH + jj;
  if (k < Ktot) {
    const int klog = 32 * (k >> 5) + invP(k & 31);
    float v = (klog < Kin) ? Wih[(size_t)orow * Kin + klog] : Whh[(size_t)orow * HH + (klog - Kin)];
    Wr[(size_t)row * Ktot + k] = (_Float16)v;
  }
  if (blockIdx.x == 0 && threadIdx.x == 0) biasr[row] = bih[orow] + bhh[orow];
}

// ---- K-permuted copy of Wfc (matches frag-major h read order) ----
__global__ __launch_bounds__(256) void prep_wfc_kernel(const float* __restrict__ Wfc,
                                                       float* __restrict__ wfcp) {
  const int n = blockIdx.x * blockDim.x + threadIdx.x;      // o*HH + k_store
  const int k = n & (HH - 1);
  const int o = n >> 10;
  wfcp[n] = Wfc[(size_t)o * HH + 32 * (k >> 5) + invP(k & 31)];
}

// Load one group: 8 batch-frags from frag-major panel (BASE = panel + g*BB*32)
#define LOADG(U, BASE) \
  { const _Float16* p_ = (BASE) + 8 * kl; \
    _Pragma("unroll") for (int bf_ = 0; bf_ < 8; ++bf_) \
      U[bf_] = *(const half8*)(p_ + (16 * bf_ + l15) * 32); }

#define MFMAG(ACC, U, AF) \
  { _Pragma("unroll") for (int bf_ = 0; bf_ < 8; ++bf_) \
      ACC[bf_] = __builtin_amdgcn_mfma_f32_16x16x32_f16((AF), U[bf_], ACC[bf_], 0, 0, 0); }

#define L0SRC(f) ((5 * wid + (f)) < 8 ? xt + (5 * wid + (f)) * (BB * 32) \
                                      : h0prev + ((5 * wid + (f)) - 8) * (BB * 32))
#define L1SRC(f) ((wid < 4) ? h0prev + (8 * wid + (f)) * (BB * 32) \
                            : h1prev + (8 * (wid - 4) + (f)) * (BB * 32))

// ---- persistent LSTM: weights in registers, fused 13-group pipeline, grid barrier ----
__global__ __launch_bounds__(512, 1) void lstm_persist(
    const _Float16* __restrict__ w0r, const _Float16* __restrict__ w1r,
    const float* __restrict__ bias0, const float* __restrict__ bias1,
    const _Float16* __restrict__ x16,
    _Float16* __restrict__ h0buf, _Float16* __restrict__ h1buf,
    unsigned int* cnt)
{
  __shared__ float red[8 * 2048];   // 64KB
  const int tid  = threadIdx.x;
  const int lane = tid & 63;
  const int wid  = tid >> 6;
  const int l15  = lane & 15;
  const int kl   = lane >> 4;
  const int bid  = blockIdx.x;

  // ---- A tiles -> registers, one contiguous half8 per frag ----
  half8 A0[5], A1[8];
  {
    const _Float16* base0 = w0r + (size_t)(16 * bid + l15) * K0 + 8 * kl;
    #pragma unroll
    for (int f = 0; f < 5; ++f) A0[f] = *(const half8*)(base0 + 32 * (5 * wid + f));
    const _Float16* base1 = w1r + (size_t)(16 * bid + l15) * K1 + 8 * kl;
    #pragma unroll
    for (int f = 0; f < 8; ++f) A1[f] = *(const half8*)(base1 + 32 * (8 * wid + f));
  }
  const f32x4 bs0 = *(const f32x4*)(bias0 + 16 * bid + kl * 4);
  const f32x4 bs1 = *(const f32x4*)(bias1 + 16 * bid + kl * 4);

  const int jj = 4 * bid + kl;                   // logical hidden unit this lane owns
  const int bb = 16 * wid + l15;                 // batch element this lane owns
  const size_t hwIdx = ((size_t)(jj >> 5) * BB + bb) * 32 + permP(jj & 31); // frag-major h addr
  float c0 = 0.f, c1 = 0.f;
  bool dead = false;

  #pragma unroll 1
  for (int tau = 0; tau <= TT; ++tau) {
    const _Float16* h0prev = h0buf + ((tau + 1) & 1) * (BB * HH);
    _Float16*       h0w    = h0buf + ((tau    ) & 1) * (BB * HH);
    const _Float16* h1prev = h1buf + ((tau    ) & 1) * (BB * HH);
    _Float16*       h1w    = h1buf + ((tau + 1) & 1) * (BB * HH);
    const _Float16* xt     = x16 + (size_t)tau * (BB * II);

    f32x4 acc0[8], acc1[8];
    #pragma unroll
    for (int bf = 0; bf < 8; ++bf) {
      acc0[bf] = (f32x4){0.f, 0.f, 0.f, 0.f};
      acc1[bf] = (f32x4){0.f, 0.f, 0.f, 0.f};
    }

    half8 Ua[8], Ub[8], Uc[8];
    if (tau == 0) {                       // layer 0 only
      LOADG(Ua, L0SRC(0)); LOADG(Ub, L0SRC(1)); LOADG(Uc, L0SRC(2));
      MFMAG(acc0, Ua, A0[0]); LOADG(Ua, L0SRC(3));
      MFMAG(acc0, Ub, A0[1]); LOADG(Ub, L0SRC(4));
      MFMAG(acc0, Uc, A0[2]);
      MFMAG(acc0, Ua, A0[3]);
      MFMAG(acc0, Ub, A0[4]);
    } else if (tau == TT) {               // layer 1 only
      LOADG(Ua, L1SRC(0)); LOADG(Ub, L1SRC(1)); LOADG(Uc, L1SRC(2));
      MFMAG(acc1, Ua, A1[0]); LOADG(Ua, L1SRC(3));
      MFMAG(acc1, Ub, A1[1]); LOADG(Ub, L1SRC(4));
      MFMAG(acc1, Uc, A1[2]); LOADG(Uc, L1SRC(5));
      MFMAG(acc1, Ua, A1[3]); LOADG(Ua, L1SRC(6));
      MFMAG(acc1, Ub, A1[4]); LOADG(Ub, L1SRC(7));
      MFMAG(acc1, Uc, A1[5]);
      MFMAG(acc1, Ua, A1[6]);
      MFMAG(acc1, Ub, A1[7]);
    } else {                              // fused 13-group pipeline
      LOADG(Ua, L0SRC(0)); LOADG(Ub, L0SRC(1)); LOADG(Uc, L0SRC(2));
      MFMAG(acc0, Ua, A0[0]); LOADG(Ua, L0SRC(3));
      MFMAG(acc0, Ub, A0[1]); LOADG(Ub, L0SRC(4));
      MFMAG(acc0, Uc, A0[2]); LOADG(Uc, L1SRC(0));
      MFMAG(acc0, Ua, A0[3]); LOADG(Ua, L1SRC(1));
      MFMAG(acc0, Ub, A0[4]); LOADG(Ub, L1SRC(2));
      MFMAG(acc1, Uc, A1[0]); LOADG(Uc, L1SRC(3));
      MFMAG(acc1, Ua, A1[1]); LOADG(Ua, L1SRC(4));
      MFMAG(acc1, Ub, A1[2]); LOADG(Ub, L1SRC(5));
      MFMAG(acc1, Uc, A1[3]); LOADG(Uc, L1SRC(6));
      MFMAG(acc1, Ua, A1[4]); LOADG(Ua, L1SRC(7));
      MFMAG(acc1, Ub, A1[5]);
      MFMAG(acc1, Uc, A1[6]);
      MFMAG(acc1, Ua, A1[7]);
    }

    // ---- layer-0 reduce + cell update ----
    if (tau < TT) {
      #pragma unroll
      for (int bf = 0; bf < 8; ++bf)
        *(f32x4*)&red[wid * 2048 + bf * 256 + lane * 4] = acc0[bf];
      __syncthreads();
      f32x4 r = {0.f, 0.f, 0.f, 0.f};
      #pragma unroll
      for (int s = 0; s < 8; ++s)
        r += *(const f32x4*)&red[s * 2048 + wid * 256 + lane * 4];
      r += bs0;
      const float gi = sigmoidf_(r[0]);
      const float gf = sigmoidf_(r[1]);
      const float gg = tanhf(r[2]);
      const float go = sigmoidf_(r[3]);
      c0 = gf * c0 + gi * gg;
      h0w[hwIdx] = (_Float16)(go * tanhf(c0));
    }
    if (tau >= 1 && tau < TT) __syncthreads();
    // ---- layer-1 reduce + cell update ----
    if (tau >= 1) {
      #pragma unroll
      for (int bf = 0; bf < 8; ++bf)
        *(f32x4*)&red[wid * 2048 + bf * 256 + lane * 4] = acc1[bf];
      __syncthreads();
      f32x4 r = {0.f, 0.f, 0.f, 0.f};
      #pragma unroll
      for (int s = 0; s < 8; ++s)
        r += *(const f32x4*)&red[s * 2048 + wid * 256 + lane * 4];
      r += bs1;
      const float gi = sigmoidf_(r[0]);
      const float gf = sigmoidf_(r[1]);
      const float gg = tanhf(r[2]);
      const float go = sigmoidf_(r[3]);
      c1 = gf * c1 + gi * gg;
      h1w[hwIdx] = (_Float16)(go * tanhf(c1));
    }

    // ---- grid barrier ----
    if (tau < TT) {
      __syncthreads();
      if (tid == 0) {
        __threadfence();
        __hip_atomic_fetch_add(cnt, 1u, __ATOMIC_ACQ_REL, __HIP_MEMORY_SCOPE_AGENT);
        const unsigned int target = 256u * (unsigned int)(tau + 1);
        if (!dead) {
          int guard = 0;
          while (__hip_atomic_load(cnt, __ATOMIC_ACQUIRE, __HIP_MEMORY_SCOPE_AGENT) < target) {
            __builtin_amdgcn_s_sleep(1);
            if (++guard > (1 << 20)) { dead = true; break; }
          }
        }
        __threadfence();
      }
      __syncthreads();
    }
  }
}

// ---- final projection on frag-major perm'd h + perm'd Wfc ----
__global__ __launch_bounds__(128) void fc_kernel(const _Float16* __restrict__ h,
    const float* __restrict__ wfcp, const float* __restrict__ bfc, float* __restrict__ out) {
  const int b = blockIdx.x;
  const int o = threadIdx.x;
  const float* wr = wfcp + (size_t)o * HH;
  float s = 0.f;
  #pragma unroll 2
  for (int g = 0; g < 32; ++g) {
    const _Float16* hr = h + ((size_t)g * BB + b) * 32;
    const float* w = wr + g * 32;
    #pragma unroll
    for (int k = 0; k < 32; k += 4) {
      float4 wv = *(const float4*)(w + k);
      half4v hv = *(const half4v*)(hr + k);
      s += (float)hv[0]*wv.x + (float)hv[1]*wv.y + (float)hv[2]*wv.z + (float)hv[3]*wv.w;
    }
  }
  out[(size_t)b * 128 + o] = s + bfc[o];
}

extern "C" void kernel_launch(void* const* d_in, const int* in_sizes, int n_in,
                              void* d_out, int out_size, void* d_ws, size_t ws_size,
                              hipStream_t stream) {
  const float* x    = (const float*)d_in[0];
  const float* Wih0 = (const float*)d_in[1];
  const float* Whh0 = (const float*)d_in[2];
  const float* bih0 = (const float*)d_in[3];
  const float* bhh0 = (const float*)d_in[4];
  const float* Wih1 = (const float*)d_in[5];
  const float* Whh1 = (const float*)d_in[6];
  const float* bih1 = (const float*)d_in[7];
  const float* bhh1 = (const float*)d_in[8];
  const float* Wfc  = (const float*)d_in[9];
  const float* bfc  = (const float*)d_in[10];
  float* out = (float*)d_out;

  char* ws = (char*)d_ws;
  size_t off = 0;
  auto alloc = [&](size_t bytes) -> void* {
    void* p = ws + off;
    off += (bytes + 255) & ~(size_t)255;
    return p;
  };
  _Float16* x16 = (_Float16*)alloc((size_t)BB * TT * II * 2);
  _Float16* w0r = (_Float16*)alloc((size_t)4096 * K0 * 2);
  _Float16* w1r = (_Float16*)alloc((size_t)4096 * K1 * 2);
  float* bias0  = (float*)alloc(4096 * 4);
  float* bias1  = (float*)alloc(4096 * 4);
  float* wfcp   = (float*)alloc((size_t)128 * HH * 4);
  const size_t stateBytes = 256 + (size_t)2 * BB * HH * 2 * 2;
  char* states  = (char*)alloc(stateBytes);
  unsigned int* cnt = (unsigned int*)states;
  _Float16* h0buf = (_Float16*)(states + 256);
  _Float16* h1buf = h0buf + 2 * BB * HH;

  hipMemsetAsync(states, 0, stateBytes, stream);

  cvt_x_kernel<<<dim3(BB * TT * II / 8 / 256), 256, 0, stream>>>(x, x16);
  prep_w_kernel<<<dim3(K0 / 256, 4096), 256, 0, stream>>>(Wih0, Whh0, bih0, bhh0, w0r, bias0, II);
  prep_w_kernel<<<dim3(K1 / 256, 4096), 256, 0, stream>>>(Wih1, Whh1, bih1, bhh1, w1r, bias1, HH);
  prep_wfc_kernel<<<dim3(128 * HH / 256), 256, 0, stream>>>(Wfc, wfcp);

  void* args[] = { (void*)&w0r, (void*)&w1r, (void*)&bias0, (void*)&bias1,
                   (void*)&x16, (void*)&h0buf, (void*)&h1buf, (void*)&cnt };
  hipLaunchCooperativeKernel((void*)lstm_persist, dim3(256), dim3(512), args, 0, stream);

  fc_kernel<<<dim3(BB), 128, 0, stream>>>(h1buf + (size_t)BB * HH, wfcp, bfc, out);
}

// Round 5
// 10873.994 us; speedup vs baseline: 3.5481x; 1.7275x over previous
//
#include <hip/hip_runtime.h>
#include <cmath>

#define BB 128
#define TT 512
#define II 256
#define HH 1024
#define K0 1280            // layer0 K (256 x + 1024 h)
#define K1 2048            // layer1 K (1024 feed + 1024 rec)
#define FRAG (BB * 32)     // elems per k-frag panel [128 batch][32 k]

typedef _Float16 half4v __attribute__((ext_vector_type(4)));
typedef _Float16 half8  __attribute__((ext_vector_type(8)));
typedef float    f32x4  __attribute__((ext_vector_type(4)));

__device__ __forceinline__ float sigmoidf_(float x) { return 1.0f / (1.0f + __expf(-x)); }
__device__ __forceinline__ float tanhf_(float x) {
  float xc = fminf(fmaxf(x, -15.f), 15.f);
  float e = __expf(2.f * xc);
  return (e - 1.f) / (e + 1.f);
}

// K-perm within each 32-block: storage p -> logical o
__device__ __host__ __forceinline__ int invP(int p) {
  return 16 * ((p >> 2) & 1) + 4 * (p >> 3) + (p & 3);
}
__device__ __forceinline__ int permP(int o) {
  return 8 * ((o & 15) >> 2) + 4 * (o >> 4) + (o & 3);
}

// ---- convert x fp32 [B][T][I] -> fp16 frag-major [T][g=I/32][B][32perm] ----
__global__ __launch_bounds__(256) void cvt_x_kernel(const float* __restrict__ x,
                                                    _Float16* __restrict__ x16) {
  const int n = blockIdx.x * blockDim.x + threadIdx.x;
  const int q   = n & 3;
  const int b   = (n >> 2) & (BB - 1);
  const int tg  = n >> 9;
  const int t = tg >> 3;
  const int g = tg & 7;
  const float* src = x + ((size_t)b * TT + t) * II + 32 * g;
  const float4 lo = *(const float4*)(src + 4 * q);
  const float4 hi = *(const float4*)(src + 16 + 4 * q);
  half8 o = { (_Float16)lo.x, (_Float16)lo.y, (_Float16)lo.z, (_Float16)lo.w,
              (_Float16)hi.x, (_Float16)hi.y, (_Float16)hi.z, (_Float16)hi.w };
  *(half8*)(x16 + ((size_t)tg * BB + b) * 32 + 8 * q) = o;
}

// ---- gate-interleaved + K-permuted fp16 weight [4096][Ktot]; row' = 4*j + gate ----
__global__ __launch_bounds__(256) void prep_w_kernel(const float* __restrict__ Wih,
    const float* __restrict__ Whh, const float* __restrict__ bih, const float* __restrict__ bhh,
    _Float16* __restrict__ Wr, float* __restrict__ biasr, int Kin) {
  const int Ktot = Kin + HH;
  const int row  = blockIdx.y;
  const int k    = blockIdx.x * blockDim.x + threadIdx.x;
  const int jj = row >> 2, gate = row & 3;
  const int orow = gate * HH + jj;
  if (k < Ktot) {
    const int klog = 32 * (k >> 5) + invP(k & 31);
    float v = (klog < Kin) ? Wih[(size_t)orow * Kin + klog] : Whh[(size_t)orow * HH + (klog - Kin)];
    Wr[(size_t)row * Ktot + k] = (_Float16)v;
  }
  if (blockIdx.x == 0 && threadIdx.x == 0) biasr[row] = bih[orow] + bhh[orow];
}

// ---- K-permuted copy of Wfc ----
__global__ __launch_bounds__(256) void prep_wfc_kernel(const float* __restrict__ Wfc,
                                                       float* __restrict__ wfcp) {
  const int n = blockIdx.x * blockDim.x + threadIdx.x;
  const int k = n & (HH - 1);
  const int o = n >> 10;
  wfcp[n] = Wfc[(size_t)o * HH + 32 * (k >> 5) + invP(k & 31)];
}

#define SB __builtin_amdgcn_sched_barrier(0)

// load one k-frag group: 4 batch-frags of this group's 64-batch slab
#define LOADG(U, BASE) { \
  const _Float16* p_ = (BASE) + boff; \
  U[0] = *(const half8*)(p_); \
  U[1] = *(const half8*)(p_ + 512); \
  U[2] = *(const half8*)(p_ + 1024); \
  U[3] = *(const half8*)(p_ + 1536); }

// 8 MFMAs: 2 row-tiles x 4 batch-frags, k-frag index kf (literal)
#define MFMA8(ACC, U, Aarr, kf) { \
  _Pragma("unroll") for (int f_ = 0; f_ < 4; ++f_) { \
    ACC[0][f_] = __builtin_amdgcn_mfma_f32_16x16x32_f16(Aarr[0][kf], U[f_], ACC[0][f_], 0, 0, 0); \
    ACC[1][f_] = __builtin_amdgcn_mfma_f32_16x16x32_f16(Aarr[1][kf], U[f_], ACC[1][f_], 0, 0, 0); } }

#define L0SRC(f) ((5 * wid + (f)) < 8 ? xt + (5 * wid + (f)) * FRAG \
                                      : h0prev + ((5 * wid + (f)) - 8) * FRAG)
#define L1SRC(f) ((wid < 4) ? h0prev + (8 * wid + (f)) * FRAG \
                            : h1prev + (8 * (wid - 4) + (f)) * FRAG)

// ---- persistent LSTM: G=2 batch split, weights in registers, pinned pipeline ----
// 256 blocks x 512 thr. Block (grp = bid>>7, lbid = bid&127) owns gate-rows
// 32*lbid..+31 (2 tiles of 16) of both layers, batch slab grp*64..+63 (4 bfrags).
// 8 waves K-split; LDS reduce; lane owns one (hidden j, batch b) pair.
__global__ __launch_bounds__(512, 1) void lstm_persist(
    const _Float16* __restrict__ w0r, const _Float16* __restrict__ w1r,
    const float* __restrict__ bias0, const float* __restrict__ bias1,
    const _Float16* __restrict__ x16,
    _Float16* __restrict__ h0buf, _Float16* __restrict__ h1buf,
    unsigned int* cnt)
{
  __shared__ float red[8 * 2048];   // 64KB
  const int tid  = threadIdx.x;
  const int lane = tid & 63;
  const int wid  = tid >> 6;
  const int l15  = lane & 15;
  const int kl   = lane >> 4;
  const int bid  = blockIdx.x;
  const int grp  = bid >> 7;
  const int lbid = bid & 127;

  // ---- A tiles -> registers: 2 row-tiles, K-slice per wave ----
  half8 A0[2][5], A1[2][8];
  #pragma unroll
  for (int t = 0; t < 2; ++t) {
    const _Float16* base0 = w0r + (size_t)(32 * lbid + 16 * t + l15) * K0 + 8 * kl;
    #pragma unroll
    for (int f = 0; f < 5; ++f) A0[t][f] = *(const half8*)(base0 + 32 * (5 * wid + f));
    const _Float16* base1 = w1r + (size_t)(32 * lbid + 16 * t + l15) * K1 + 8 * kl;
    #pragma unroll
    for (int f = 0; f < 8; ++f) A1[t][f] = *(const half8*)(base1 + 32 * (8 * wid + f));
  }
  const int t_own = wid >> 2, f_own = wid & 3;
  const f32x4 bs0 = *(const f32x4*)(bias0 + 32 * lbid + 16 * t_own + 4 * kl);
  const f32x4 bs1 = *(const f32x4*)(bias1 + 32 * lbid + 16 * t_own + 4 * kl);

  const int jj = 8 * lbid + 4 * t_own + kl;          // hidden unit this lane owns
  const int bb = 64 * grp + 16 * f_own + l15;        // batch element this lane owns
  const size_t hwIdx = ((size_t)(jj >> 5) * BB + bb) * 32 + permP(jj & 31);
  const int boff = grp * 2048 + l15 * 32 + 8 * kl;   // within-frag load offset
  unsigned int* mycnt = cnt + grp * 64;              // separate cache lines per group
  float c0 = 0.f, c1 = 0.f;
  bool dead = false;

  #pragma unroll 1
  for (int tau = 0; tau <= TT; ++tau) {
    const _Float16* h0prev = h0buf + ((tau + 1) & 1) * (BB * HH);
    _Float16*       h0w    = h0buf + ((tau    ) & 1) * (BB * HH);
    const _Float16* h1prev = h1buf + ((tau    ) & 1) * (BB * HH);
    _Float16*       h1w    = h1buf + ((tau + 1) & 1) * (BB * HH);
    const _Float16* xt     = x16 + (size_t)tau * (BB * II);

    f32x4 acc0[2][4], acc1[2][4];
    #pragma unroll
    for (int t = 0; t < 2; ++t)
      #pragma unroll
      for (int f = 0; f < 4; ++f) {
        acc0[t][f] = (f32x4){0.f, 0.f, 0.f, 0.f};
        acc1[t][f] = (f32x4){0.f, 0.f, 0.f, 0.f};
      }

    half8 Ua[4], Ub[4], Uc[4];
    if (tau == 0) {                       // layer 0 only
      LOADG(Ua, L0SRC(0)); SB;
      LOADG(Ub, L0SRC(1)); SB;
      LOADG(Uc, L0SRC(2)); SB;
      MFMA8(acc0, Ua, A0, 0); LOADG(Ua, L0SRC(3)); SB;
      MFMA8(acc0, Ub, A0, 1); LOADG(Ub, L0SRC(4)); SB;
      MFMA8(acc0, Uc, A0, 2); SB;
      MFMA8(acc0, Ua, A0, 3); SB;
      MFMA8(acc0, Ub, A0, 4);
    } else if (tau == TT) {               // layer 1 only
      LOADG(Ua, L1SRC(0)); SB;
      LOADG(Ub, L1SRC(1)); SB;
      LOADG(Uc, L1SRC(2)); SB;
      MFMA8(acc1, Ua, A1, 0); LOADG(Ua, L1SRC(3)); SB;
      MFMA8(acc1, Ub, A1, 1); LOADG(Ub, L1SRC(4)); SB;
      MFMA8(acc1, Uc, A1, 2); LOADG(Uc, L1SRC(5)); SB;
      MFMA8(acc1, Ua, A1, 3); LOADG(Ua, L1SRC(6)); SB;
      MFMA8(acc1, Ub, A1, 4); LOADG(Ub, L1SRC(7)); SB;
      MFMA8(acc1, Uc, A1, 5); SB;
      MFMA8(acc1, Ua, A1, 6); SB;
      MFMA8(acc1, Ub, A1, 7);
    } else {                              // fused 13-group pipeline
      LOADG(Ua, L0SRC(0)); SB;
      LOADG(Ub, L0SRC(1)); SB;
      LOADG(Uc, L0SRC(2)); SB;
      MFMA8(acc0, Ua, A0, 0); LOADG(Ua, L0SRC(3)); SB;
      MFMA8(acc0, Ub, A0, 1); LOADG(Ub, L0SRC(4)); SB;
      MFMA8(acc0, Uc, A0, 2); LOADG(Uc, L1SRC(0)); SB;
      MFMA8(acc0, Ua, A0, 3); LOADG(Ua, L1SRC(1)); SB;
      MFMA8(acc0, Ub, A0, 4); LOADG(Ub, L1SRC(2)); SB;
      MFMA8(acc1, Uc, A1, 0); LOADG(Uc, L1SRC(3)); SB;
      MFMA8(acc1, Ua, A1, 1); LOADG(Ua, L1SRC(4)); SB;
      MFMA8(acc1, Ub, A1, 2); LOADG(Ub, L1SRC(5)); SB;
      MFMA8(acc1, Uc, A1, 3); LOADG(Uc, L1SRC(6)); SB;
      MFMA8(acc1, Ua, A1, 4); LOADG(Ua, L1SRC(7)); SB;
      MFMA8(acc1, Ub, A1, 5); SB;
      MFMA8(acc1, Uc, A1, 6); SB;
      MFMA8(acc1, Ua, A1, 7);
    }

    // ---- layer-0 reduce + cell update ----
    if (tau < TT) {
      #pragma unroll
      for (int t = 0; t < 2; ++t)
        #pragma unroll
        for (int f = 0; f < 4; ++f)
          *(f32x4*)&red[wid * 2048 + (t * 4 + f) * 256 + lane * 4] = acc0[t][f];
      __syncthreads();
      f32x4 r = {0.f, 0.f, 0.f, 0.f};
      #pragma unroll
      for (int s = 0; s < 8; ++s)
        r += *(const f32x4*)&red[s * 2048 + wid * 256 + lane * 4];
      r += bs0;
      const float gi = sigmoidf_(r[0]);
      const float gf = sigmoidf_(r[1]);
      const float gg = tanhf_(r[2]);
      const float go = sigmoidf_(r[3]);
      c0 = gf * c0 + gi * gg;
      h0w[hwIdx] = (_Float16)(go * tanhf_(c0));
    }
    if (tau >= 1 && tau < TT) __syncthreads();
    // ---- layer-1 reduce + cell update ----
    if (tau >= 1) {
      #pragma unroll
      for (int t = 0; t < 2; ++t)
        #pragma unroll
        for (int f = 0; f < 4; ++f)
          *(f32x4*)&red[wid * 2048 + (t * 4 + f) * 256 + lane * 4] = acc1[t][f];
      __syncthreads();
      f32x4 r = {0.f, 0.f, 0.f, 0.f};
      #pragma unroll
      for (int s = 0; s < 8; ++s)
        r += *(const f32x4*)&red[s * 2048 + wid * 256 + lane * 4];
      r += bs1;
      const float gi = sigmoidf_(r[0]);
      const float gf = sigmoidf_(r[1]);
      const float gg = tanhf_(r[2]);
      const float go = sigmoidf_(r[3]);
      c1 = gf * c1 + gi * gg;
      h1w[hwIdx] = (_Float16)(go * tanhf_(c1));
    }

    // ---- per-group grid barrier: release-add, relaxed spin, one acquire fence ----
    if (tau < TT) {
      __syncthreads();
      if (tid == 0) {
        __builtin_amdgcn_fence(__ATOMIC_RELEASE, "agent");
        __hip_atomic_fetch_add(mycnt, 1u, __ATOMIC_RELAXED, __HIP_MEMORY_SCOPE_AGENT);
        const unsigned int target = 128u * (unsigned int)(tau + 1);
        if (!dead) {
          int guard = 0;
          while (__hip_atomic_load(mycnt, __ATOMIC_RELAXED, __HIP_MEMORY_SCOPE_AGENT) < target) {
            __builtin_amdgcn_s_sleep(4);
            if (++guard > (1 << 18)) { dead = true; break; }
          }
        }
        __builtin_amdgcn_fence(__ATOMIC_ACQUIRE, "agent");
      }
      __syncthreads();
    }
  }
}

// ---- final projection on frag-major perm'd h + perm'd Wfc ----
__global__ __launch_bounds__(128) void fc_kernel(const _Float16* __restrict__ h,
    const float* __restrict__ wfcp, const float* __restrict__ bfc, float* __restrict__ out) {
  const int b = blockIdx.x;
  const int o = threadIdx.x;
  const float* wr = wfcp + (size_t)o * HH;
  float s = 0.f;
  #pragma unroll 2
  for (int g = 0; g < 32; ++g) {
    const _Float16* hr = h + ((size_t)g * BB + b) * 32;
    const float* w = wr + g * 32;
    #pragma unroll
    for (int k = 0; k < 32; k += 4) {
      float4 wv = *(const float4*)(w + k);
      half4v hv = *(const half4v*)(hr + k);
      s += (float)hv[0]*wv.x + (float)hv[1]*wv.y + (float)hv[2]*wv.z + (float)hv[3]*wv.w;
    }
  }
  out[(size_t)b * 128 + o] = s + bfc[o];
}

extern "C" void kernel_launch(void* const* d_in, const int* in_sizes, int n_in,
                              void* d_out, int out_size, void* d_ws, size_t ws_size,
                              hipStream_t stream) {
  const float* x    = (const float*)d_in[0];
  const float* Wih0 = (const float*)d_in[1];
  const float* Whh0 = (const float*)d_in[2];
  const float* bih0 = (const float*)d_in[3];
  const float* bhh0 = (const float*)d_in[4];
  const float* Wih1 = (const float*)d_in[5];
  const float* Whh1 = (const float*)d_in[6];
  const float* bih1 = (const float*)d_in[7];
  const float* bhh1 = (const float*)d_in[8];
  const float* Wfc  = (const float*)d_in[9];
  const float* bfc  = (const float*)d_in[10];
  float* out = (float*)d_out;

  char* ws = (char*)d_ws;
  size_t off = 0;
  auto alloc = [&](size_t bytes) -> void* {
    void* p = ws + off;
    off += (bytes + 255) & ~(size_t)255;
    return p;
  };
  _Float16* x16 = (_Float16*)alloc((size_t)BB * TT * II * 2);
  _Float16* w0r = (_Float16*)alloc((size_t)4096 * K0 * 2);
  _Float16* w1r = (_Float16*)alloc((size_t)4096 * K1 * 2);
  float* bias0  = (float*)alloc(4096 * 4);
  float* bias1  = (float*)alloc(4096 * 4);
  float* wfcp   = (float*)alloc((size_t)128 * HH * 4);
  const size_t stateBytes = 512 + (size_t)2 * BB * HH * 2 * 2;
  char* states  = (char*)alloc(stateBytes);
  unsigned int* cnt = (unsigned int*)states;           // [0] grp0, [64] grp1
  _Float16* h0buf = (_Float16*)(states + 512);
  _Float16* h1buf = h0buf + 2 * BB * HH;

  hipMemsetAsync(states, 0, stateBytes, stream);

  cvt_x_kernel<<<dim3(BB * TT * II / 8 / 256), 256, 0, stream>>>(x, x16);
  prep_w_kernel<<<dim3(K0 / 256, 4096), 256, 0, stream>>>(Wih0, Whh0, bih0, bhh0, w0r, bias0, II);
  prep_w_kernel<<<dim3(K1 / 256, 4096), 256, 0, stream>>>(Wih1, Whh1, bih1, bhh1, w1r, bias1, HH);
  prep_wfc_kernel<<<dim3(128 * HH / 256), 256, 0, stream>>>(Wfc, wfcp);

  void* args[] = { (void*)&w0r, (void*)&w1r, (void*)&bias0, (void*)&bias1,
                   (void*)&x16, (void*)&h0buf, (void*)&h1buf, (void*)&cnt };
  hipLaunchCooperativeKernel((void*)lstm_persist, dim3(256), dim3(512), args, 0, stream);

  fc_kernel<<<dim3(BB), 128, 0, stream>>>(h1buf + (size_t)BB * HH, wfcp, bfc, out);
}